// Round 1
// baseline (36.062 us; speedup 1.0000x reference)
//
#include <hip/hip_runtime.h>
#include <hip/hip_bf16.h>
#include <float.h>

// VQ bottleneck: per-dim scalar nearest-codebook quantization.
// encoded: (2048, 256) f32, emb: (256, 512) f32.
// out: latent (2048*256) f32 ++ loss (1) f32.

#define NSAMP 2048
#define NDIM  256
#define NCODE 512

#define DTILE 16          // dims per block
#define NT    64          // samples per block
#define CB_STRIDE 516     // 512 + 4 pad: keeps 16B alignment, avoids bank conflicts
#define NDT   (NDIM / DTILE)    // 16 d-tiles
#define NNB   (NSAMP / NT)      // 32 n-tiles  -> grid 512

__global__ __launch_bounds__(256)
void vq_kernel(const float* __restrict__ enc,
               const float* __restrict__ emb,
               float* __restrict__ out,
               float* __restrict__ ws)
{
    __shared__ float cb[DTILE * CB_STRIDE];
    __shared__ float red[4];

    const int tid = threadIdx.x;
    const int bid = blockIdx.x;
    const int dt  = bid & (NDT - 1);   // d-tile index: consecutive blocks share emb tile
    const int nb  = bid >> 4;          // n-tile index
    const int d0  = dt * DTILE;

    // ---- stage codebook tile (16 dims x 512 codes) into LDS, float4 loads ----
    // global: emb[(d0+d)*512 + j]; rows of 512 are float4-divisible.
    {
        const float4* src = reinterpret_cast<const float4*>(emb + d0 * NCODE);
        for (int i4 = tid; i4 < DTILE * NCODE / 4; i4 += 256) {
            float4 v = src[i4];
            int i = i4 * 4;
            int d = i >> 9;          // / 512
            int j = i & (NCODE - 1);
            *reinterpret_cast<float4*>(&cb[d * CB_STRIDE + j]) = v;
        }
    }
    __syncthreads();

    const int dlocal = tid & (DTILE - 1);
    const int nrow   = tid >> 4;               // 0..15
    const int nbase  = nb * NT + nrow;         // items: nbase + 16*k, k=0..3
    const int dcol   = d0 + dlocal;

    float x[4], bestd2[4], bestval[4];
#pragma unroll
    for (int k = 0; k < 4; ++k) {
        x[k] = enc[(nbase + 16 * k) * NDIM + dcol];
        bestd2[k]  = FLT_MAX;
        bestval[k] = 0.0f;
    }

    const float* cbrow = &cb[dlocal * CB_STRIDE];

    // ---- scan 512 codes, ascending j, strict < keeps FIRST min (np.argmin tie-break)
    for (int j = 0; j < NCODE; j += 4) {
        float4 c4 = *reinterpret_cast<const float4*>(cbrow + j);
        float cc[4] = {c4.x, c4.y, c4.z, c4.w};
#pragma unroll
        for (int c = 0; c < 4; ++c) {
#pragma unroll
            for (int k = 0; k < 4; ++k) {
                float diff = x[k] - cc[c];
                float d2   = diff * diff;           // identical rounding to reference
                if (d2 < bestd2[k]) {
                    bestd2[k]  = d2;
                    bestval[k] = cc[c];
                }
            }
        }
    }

    // ---- write latent values ----
#pragma unroll
    for (int k = 0; k < 4; ++k) {
        out[(nbase + 16 * k) * NDIM + dcol] = bestval[k];
    }

    // ---- loss partial: sum of min squared distances ----
    float acc = bestd2[0] + bestd2[1] + bestd2[2] + bestd2[3];
#pragma unroll
    for (int off = 32; off > 0; off >>= 1)
        acc += __shfl_down(acc, off, 64);

    const int wid = tid >> 6;
    if ((tid & 63) == 0) red[wid] = acc;
    __syncthreads();
    if (tid == 0)
        ws[bid] = red[0] + red[1] + red[2] + red[3];
}

__global__ __launch_bounds__(512)
void vq_reduce(const float* __restrict__ ws, float* __restrict__ out)
{
    __shared__ float red[8];
    const int tid = threadIdx.x;
    float acc = ws[tid];                 // 512 partials, one per block
#pragma unroll
    for (int off = 32; off > 0; off >>= 1)
        acc += __shfl_down(acc, off, 64);
    const int wid = tid >> 6;
    if ((tid & 63) == 0) red[wid] = acc;
    __syncthreads();
    if (tid == 0) {
        float s = 0.0f;
#pragma unroll
        for (int w = 0; w < 8; ++w) s += red[w];
        out[NSAMP * NDIM] = 2.0f * s;    // vq_loss + commitment_loss
    }
}

extern "C" void kernel_launch(void* const* d_in, const int* in_sizes, int n_in,
                              void* d_out, int out_size, void* d_ws, size_t ws_size,
                              hipStream_t stream)
{
    const float* enc = (const float*)d_in[0];   // (2048, 256)
    const float* emb = (const float*)d_in[1];   // (1, 256, 512)
    float* out = (float*)d_out;                 // latent (2048*256) ++ loss (1)
    float* ws  = (float*)d_ws;                  // 512 block partials

    vq_kernel<<<NDT * NNB, 256, 0, stream>>>(enc, emb, out, ws);
    vq_reduce<<<1, 512, 0, stream>>>(ws, out);
}

// Round 2
// 22.244 us; speedup vs baseline: 1.6212x; 1.6212x over previous
//
#include <hip/hip_runtime.h>
#include <hip/hip_bf16.h>
#include <float.h>

// VQ bottleneck via per-dim sorted codebook + binary search.
// encoded: (2048, 256) f32, emb: (1, 256, 512) f32.
// out: latent (2048*256) f32 ++ loss (1) f32.
//
// Key fact: d2 = fl(fl(x-c)^2) is monotone in |x-c| on each side of x,
// so argmin over codes is one of the two sorted-order neighbors of x.
// Sort carries original indices so the np.argmin first-index tie-break
// (x exactly midway, rounded d2 equal) is reproduced exactly.

#define NSAMP 2048
#define NDIM  256
#define NCODE 512

__global__ __launch_bounds__(512)
void vq_sort_search(const float* __restrict__ enc,
                    const float* __restrict__ emb,
                    float* __restrict__ out,
                    float* __restrict__ ws)
{
    __shared__ float sval[NCODE];
    __shared__ int   sidx[NCODE];
    __shared__ float red[8];

    const int tid = threadIdx.x;
    const int d   = blockIdx.x;          // one block per dimension

    // ---- load codebook row for this dim ----
    sval[tid] = emb[d * NCODE + tid];
    sidx[tid] = tid;

    // ---- bitonic sort 512 (value, index) pairs ascending ----
    // total order: value asc, then index asc (handles duplicate values).
    for (int k = 2; k <= NCODE; k <<= 1) {
        for (int j = k >> 1; j > 0; j >>= 1) {
            __syncthreads();
            const int i = tid, ixj = i ^ j;
            if (ixj > i) {
                float vi = sval[i], vj = sval[ixj];
                int   ii = sidx[i], ij = sidx[ixj];
                bool agt = (vi > vj) || (vi == vj && ii > ij);
                bool up  = ((i & k) == 0);
                if (agt == up) {
                    sval[i] = vj; sval[ixj] = vi;
                    sidx[i] = ij; sidx[ixj] = ii;
                }
            }
        }
    }
    __syncthreads();

    // ---- each thread quantizes 4 elements of this dim's column ----
    float acc = 0.0f;
#pragma unroll
    for (int kk = 0; kk < NSAMP / 512; ++kk) {
        const int n = tid + 512 * kk;
        const float x = enc[n * NDIM + d];

        // lower_bound: p = #(sval < x), in [0, 512].
        // 9-step loop yields min(count, 511); fixup handles count==512.
        int p = 0;
#pragma unroll
        for (int s = NCODE / 2; s > 0; s >>= 1)
            if (sval[p + s - 1] < x) p += s;
        if (sval[p] < x) ++p;

        float d2l = FLT_MAX, d2r = FLT_MAX, vl = 0.0f, vr = 0.0f;
        int   il = 0x7fffffff, ir = 0x7fffffff;
        if (p > 0) {
            vl = sval[p - 1]; il = sidx[p - 1];
            float t = x - vl;          // same rounding as reference
            d2l = t * t;
        }
        if (p < NCODE) {
            vr = sval[p]; ir = sidx[p];
            float t = x - vr;
            d2r = t * t;
        }

        float outv;
        if (d2l < d2r)      outv = vl;
        else if (d2r < d2l) outv = vr;
        else                outv = (il < ir) ? vl : vr;  // exact tie: first original index

        out[n * NDIM + d] = outv;
        acc += fminf(d2l, d2r);
    }

    // ---- block partial of sum(min d2) ----
#pragma unroll
    for (int off = 32; off > 0; off >>= 1)
        acc += __shfl_down(acc, off, 64);
    if ((tid & 63) == 0) red[tid >> 6] = acc;
    __syncthreads();
    if (tid == 0) {
        float s = 0.0f;
#pragma unroll
        for (int w = 0; w < 8; ++w) s += red[w];
        ws[d] = s;
    }
}

__global__ __launch_bounds__(256)
void vq_reduce(const float* __restrict__ ws, float* __restrict__ out)
{
    __shared__ float red[4];
    const int tid = threadIdx.x;
    float acc = ws[tid];                 // 256 partials, one per dim
#pragma unroll
    for (int off = 32; off > 0; off >>= 1)
        acc += __shfl_down(acc, off, 64);
    if ((tid & 63) == 0) red[tid >> 6] = acc;
    __syncthreads();
    if (tid == 0)
        out[NSAMP * NDIM] = 2.0f * (red[0] + red[1] + red[2] + red[3]);
}

extern "C" void kernel_launch(void* const* d_in, const int* in_sizes, int n_in,
                              void* d_out, int out_size, void* d_ws, size_t ws_size,
                              hipStream_t stream)
{
    const float* enc = (const float*)d_in[0];   // (2048, 256)
    const float* emb = (const float*)d_in[1];   // (1, 256, 512)
    float* out = (float*)d_out;                 // latent ++ loss
    float* ws  = (float*)d_ws;                  // 256 per-dim partials

    vq_sort_search<<<NDIM, 512, 0, stream>>>(enc, emb, out, ws);
    vq_reduce<<<1, NDIM, 0, stream>>>(ws, out);
}

// Round 3
// 21.695 us; speedup vs baseline: 1.6622x; 1.0253x over previous
//
#include <hip/hip_runtime.h>
#include <hip/hip_bf16.h>
#include <float.h>

// VQ bottleneck: per-dim scalar nearest-codebook quantization.
// encoded: (2048, 256) f32, emb: (1, 256, 512) f32.
// out: latent (2048*256) f32 ++ loss (1) f32.
//
// Pipeline: [sort per-dim codebook] -> [coalesced binary-search quantize] -> [loss reduce]
// d2 = fl(fl(x-c)^2) is monotone in |x-c| per side, so argmin is one of the two
// sorted-order neighbors. Sorted (val, original-idx) pairs reproduce np.argmin's
// first-index tie-break exactly for the only O(1)-error case (exact midpoint).

#define NSAMP 2048
#define NDIM  256
#define NCODE 512

// ---- ws layout ----
#define WS_VAL_OFF  0
#define WS_IDX_OFF  (NDIM * NCODE * 4)                  // 512 KB
#define WS_LOSS_OFF (WS_IDX_OFF + NDIM * NCODE * 2)     // 768 KB
#define WS_NEEDED   (WS_LOSS_OFF + 4096)

// ======================= kernel 1: per-dim bitonic sort =======================
// 256 blocks x 512 threads, one (val,idx) per thread. Stages with j<64 use
// __shfl_xor (intra-wave); only j>=64 (6 stages) touch LDS + barriers.
__global__ __launch_bounds__(512)
void vq_sort(const float* __restrict__ emb,
             float* __restrict__ wsVal,
             unsigned short* __restrict__ wsIdx)
{
    __shared__ float sv[NCODE];
    __shared__ int   si[NCODE];

    const int tid = threadIdx.x;
    const int d   = blockIdx.x;

    float v  = emb[d * NCODE + tid];
    int  idx = tid;

    for (int k = 2; k <= NCODE; k <<= 1) {
        for (int j = k >> 1; j > 0; j >>= 1) {
            float v2; int i2;
            if (j < 64) {
                v2 = __shfl_xor(v, j, 64);
                i2 = __shfl_xor(idx, j, 64);
            } else {
                sv[tid] = v; si[tid] = idx;
                __syncthreads();
                v2 = sv[tid ^ j]; i2 = si[tid ^ j];
                __syncthreads();
            }
            // total order: (val, idx) lexicographic — handles duplicate values
            bool less  = (v < v2) || (v == v2 && idx < i2);
            bool lower = (tid & j) == 0;
            bool up    = (tid & k) == 0;     // k==512: always ascending (final merge)
            if ((lower == up) != less) { v = v2; idx = i2; }
        }
    }

    wsVal[d * NCODE + tid] = v;
    wsIdx[d * NCODE + tid] = (unsigned short)idx;
}

// ======================= kernel 2: coalesced search =======================
// Block = 16 dims x 128 samples (256 threads, 8 elems/thread). Wave reads 4
// contiguous 64B segments per global access. Tables in LDS at stride 516.
#define DT 16
#define ST 128
#define CBS 516   // 512+4: keeps 16B alignment; uniform step-1 probe conflict-free

__global__ __launch_bounds__(256)
void vq_search(const float* __restrict__ enc,
               const float* __restrict__ wsVal,
               const unsigned short* __restrict__ wsIdx,
               float* __restrict__ out,
               float* __restrict__ wsLoss)
{
    __shared__ float          cbv[DT][CBS];
    __shared__ unsigned short cbi[DT][CBS];
    __shared__ float red[4];

    const int tid   = threadIdx.x;
    const int bx    = blockIdx.x;
    const int dtile = bx & (NDIM / DT - 1);   // 16 dim-tiles
    const int stile = bx >> 4;                // 16 sample-tiles
    const int d0    = dtile * DT;
    const int n0    = stile * ST;

    // ---- stage sorted tables into LDS (coalesced) ----
    {
        const float4* src = reinterpret_cast<const float4*>(wsVal + d0 * NCODE);
        for (int i4 = tid; i4 < DT * NCODE / 4; i4 += 256) {
            float4 q = src[i4];
            int i = i4 * 4, dl = i >> 9, pos = i & (NCODE - 1);
            *reinterpret_cast<float4*>(&cbv[dl][pos]) = q;
        }
        const uint2* srci = reinterpret_cast<const uint2*>(wsIdx + d0 * NCODE);
        for (int i4 = tid; i4 < DT * NCODE / 4; i4 += 256) {
            uint2 q = srci[i4];
            int i = i4 * 4, dl = i >> 9, pos = i & (NCODE - 1);
            *reinterpret_cast<uint2*>(&cbi[dl][pos]) = q;
        }
    }
    __syncthreads();

    const int dl = tid & (DT - 1);
    const float*          vrow = cbv[dl];
    const unsigned short* irow = cbi[dl];

    // ---- load 8 elements (coalesced) ----
    float x[8]; int gidx[8];
#pragma unroll
    for (int r = 0; r < 8; ++r) {
        int nl = (tid >> 4) + 16 * r;
        gidx[r] = (n0 + nl) * NDIM + d0 + dl;
        x[r] = enc[gidx[r]];
    }

    // ---- 8 interleaved branchless binary searches: p = #(val < x), capped 511 ----
    int p[8];
#pragma unroll
    for (int r = 0; r < 8; ++r) p[r] = 0;
#pragma unroll
    for (int s = NCODE / 2; s > 0; s >>= 1) {
#pragma unroll
        for (int r = 0; r < 8; ++r)
            if (vrow[p[r] + s - 1] < x[r]) p[r] += s;
    }

    float acc = 0.0f;
#pragma unroll
    for (int r = 0; r < 8; ++r) {
        int pp = p[r];
        if (vrow[pp] < x[r]) ++pp;          // count==512 fixup
        float d2l = FLT_MAX, d2r = FLT_MAX, vl = 0.0f, vr = 0.0f;
        int il = 0x7fffffff, ir = 0x7fffffff;
        if (pp > 0)     { vl = vrow[pp - 1]; il = irow[pp - 1]; float t = x[r] - vl; d2l = t * t; }
        if (pp < NCODE) { vr = vrow[pp];     ir = irow[pp];     float t = x[r] - vr; d2r = t * t; }
        float outv = (d2l < d2r) ? vl : (d2r < d2l) ? vr : ((il < ir) ? vl : vr);
        out[gidx[r]] = outv;
        acc += fminf(d2l, d2r);
    }

    // ---- block partial of sum(min d2) ----
#pragma unroll
    for (int off = 32; off > 0; off >>= 1)
        acc += __shfl_down(acc, off, 64);
    if ((tid & 63) == 0) red[tid >> 6] = acc;
    __syncthreads();
    if (tid == 0)
        wsLoss[bx] = red[0] + red[1] + red[2] + red[3];
}

// ======================= kernel 3: final loss reduce =======================
__global__ __launch_bounds__(256)
void vq_final(const float* __restrict__ wsLoss, float* __restrict__ out)
{
    __shared__ float red[4];
    const int tid = threadIdx.x;
    float acc = wsLoss[tid];              // 256 partials
#pragma unroll
    for (int off = 32; off > 0; off >>= 1)
        acc += __shfl_down(acc, off, 64);
    if ((tid & 63) == 0) red[tid >> 6] = acc;
    __syncthreads();
    if (tid == 0)
        out[NSAMP * NDIM] = 2.0f * (red[0] + red[1] + red[2] + red[3]);
}

// ======================= fallback (ws too small): R1 fused path =======================
__global__ __launch_bounds__(512)
void vq_fused_fallback(const float* __restrict__ enc,
                       const float* __restrict__ emb,
                       float* __restrict__ out,
                       float* __restrict__ ws)
{
    __shared__ float sval[NCODE];
    __shared__ int   sidx[NCODE];
    __shared__ float red[8];

    const int tid = threadIdx.x;
    const int d   = blockIdx.x;

    sval[tid] = emb[d * NCODE + tid];
    sidx[tid] = tid;
    for (int k = 2; k <= NCODE; k <<= 1) {
        for (int j = k >> 1; j > 0; j >>= 1) {
            __syncthreads();
            const int i = tid, ixj = i ^ j;
            if (ixj > i) {
                float vi = sval[i], vj = sval[ixj];
                int   ii = sidx[i], ij = sidx[ixj];
                bool agt = (vi > vj) || (vi == vj && ii > ij);
                if (agt == ((i & k) == 0)) {
                    sval[i] = vj; sval[ixj] = vi;
                    sidx[i] = ij; sidx[ixj] = ii;
                }
            }
        }
    }
    __syncthreads();

    float acc = 0.0f;
#pragma unroll
    for (int kk = 0; kk < NSAMP / 512; ++kk) {
        const int n = tid + 512 * kk;
        const float x = enc[n * NDIM + d];
        int p = 0;
#pragma unroll
        for (int s = NCODE / 2; s > 0; s >>= 1)
            if (sval[p + s - 1] < x) p += s;
        if (sval[p] < x) ++p;
        float d2l = FLT_MAX, d2r = FLT_MAX, vl = 0.0f, vr = 0.0f;
        int il = 0x7fffffff, ir = 0x7fffffff;
        if (p > 0)     { vl = sval[p - 1]; il = sidx[p - 1]; float t = x - vl; d2l = t * t; }
        if (p < NCODE) { vr = sval[p];     ir = sidx[p];     float t = x - vr; d2r = t * t; }
        out[n * NDIM + d] = (d2l < d2r) ? vl : (d2r < d2l) ? vr : ((il < ir) ? vl : vr);
        acc += fminf(d2l, d2r);
    }
#pragma unroll
    for (int off = 32; off > 0; off >>= 1)
        acc += __shfl_down(acc, off, 64);
    if ((tid & 63) == 0) red[tid >> 6] = acc;
    __syncthreads();
    if (tid == 0) {
        float s = 0.0f;
#pragma unroll
        for (int w = 0; w < 8; ++w) s += red[w];
        ws[d] = s;
    }
}

__global__ __launch_bounds__(256)
void vq_final_fallback(const float* __restrict__ ws, float* __restrict__ out)
{
    __shared__ float red[4];
    const int tid = threadIdx.x;
    float acc = ws[tid];
#pragma unroll
    for (int off = 32; off > 0; off >>= 1)
        acc += __shfl_down(acc, off, 64);
    if ((tid & 63) == 0) red[tid >> 6] = acc;
    __syncthreads();
    if (tid == 0)
        out[NSAMP * NDIM] = 2.0f * (red[0] + red[1] + red[2] + red[3]);
}

extern "C" void kernel_launch(void* const* d_in, const int* in_sizes, int n_in,
                              void* d_out, int out_size, void* d_ws, size_t ws_size,
                              hipStream_t stream)
{
    const float* enc = (const float*)d_in[0];   // (2048, 256)
    const float* emb = (const float*)d_in[1];   // (1, 256, 512)
    float* out = (float*)d_out;

    if (ws_size >= (size_t)WS_NEEDED) {
        char* ws = (char*)d_ws;
        float*          wsVal  = (float*)(ws + WS_VAL_OFF);
        unsigned short* wsIdx  = (unsigned short*)(ws + WS_IDX_OFF);
        float*          wsLoss = (float*)(ws + WS_LOSS_OFF);

        vq_sort  <<<NDIM,            512, 0, stream>>>(emb, wsVal, wsIdx);
        vq_search<<<(NSAMP/ST)*(NDIM/DT), 256, 0, stream>>>(enc, wsVal, wsIdx, out, wsLoss);
        vq_final <<<1,               256, 0, stream>>>(wsLoss, out);
    } else {
        float* ws = (float*)d_ws;   // 256 floats
        vq_fused_fallback<<<NDIM, 512, 0, stream>>>(enc, emb, out, ws);
        vq_final_fallback<<<1, NDIM, 0, stream>>>(ws, out);
    }
}